// Round 4
// baseline (200.159 us; speedup 1.0000x reference)
//
#include <hip/hip_runtime.h>

using f32x4 = __attribute__((ext_vector_type(4))) float;
using f32x16 = __attribute__((ext_vector_type(16))) float;
using s16x8 = __attribute__((ext_vector_type(8))) short;
using u16x4 = __attribute__((ext_vector_type(4))) unsigned short;

#define AS1 __attribute__((address_space(1)))
#define AS3 __attribute__((address_space(3)))

__device__ __forceinline__ void gload16(const void* g, void* l) {
  __builtin_amdgcn_global_load_lds((const AS1 unsigned int*)g,
                                   (AS3 unsigned int*)l, 16, 0, 0);
}

__device__ __forceinline__ unsigned short f2bf(float f) {
  unsigned int u = __builtin_bit_cast(unsigned int, f);
  u += 0x7fffu + ((u >> 16) & 1u);   // round-to-nearest-even
  return (unsigned short)(u >> 16);
}

__device__ __forceinline__ unsigned int cvtpk(float lo, float hi) {
  unsigned int w;
  asm("v_cvt_pk_bf16_f32 %0, %1, %2" : "=v"(w) : "v"(lo), "v"(hi));
  return w;
}

// ---------------- fused f32 -> bf16 convert (1 launch for all 5 tensors) ----
__global__ __launch_bounds__(256) void cvt_bf16_multi(
    const float* __restrict__ i0, const float* __restrict__ i1,
    const float* __restrict__ i2, const float* __restrict__ i3,
    const float* __restrict__ i4, unsigned short* __restrict__ o0,
    unsigned short* __restrict__ o1, unsigned short* __restrict__ o2,
    unsigned short* __restrict__ o3, unsigned short* __restrict__ o4) {
  int b = blockIdx.x;
  const float* in;
  unsigned short* out;
  int base, n4;
  if (b < 3072) { in = i0; out = o0; base = b; n4 = 786432; }
  else if (b < 6144) { in = i1; out = o1; base = b - 3072; n4 = 786432; }
  else if (b < 7296) { in = i2; out = o2; base = b - 6144; n4 = 294912; }
  else if (b < 7872) { in = i3; out = o3; base = b - 7296; n4 = 147456; }
  else { in = i4; out = o4; base = b - 7872; n4 = 147456; }
  int i = base * 256 + threadIdx.x;
  if (i >= n4) return;
  f32x4 v = ((const f32x4*)in)[i];
  u16x4 r;
#pragma unroll
  for (int j = 0; j < 4; ++j) r[j] = f2bf(v[j]);
  ((u16x4*)out)[i] = r;
}

// ---------------- merged projection GEMMs: qv (y<12) + k (y>=12) ------------
// C = A * B^T, A[4096][768], B[*][768] bf16; 128x128 tile, 4 waves.
__global__ __launch_bounds__(256) void gemm_proj(
    const unsigned short* __restrict__ srcb, const unsigned short* __restrict__ wqvb,
    const unsigned short* __restrict__ xb, const unsigned short* __restrict__ wkb,
    unsigned short* __restrict__ qbuf, unsigned short* __restrict__ vtbuf,
    unsigned short* __restrict__ kbuf) {
  __shared__ __align__(16) unsigned short As[128 * 64];
  __shared__ __align__(16) unsigned short Bs[128 * 64];
  const bool isqv = blockIdx.y < 12;
  const unsigned short* A = isqv ? srcb : xb;
  const unsigned short* B = isqv ? wqvb : wkb;
  const int n0 = (isqv ? blockIdx.y : (blockIdx.y - 12)) * 128;
  const int m0 = blockIdx.x * 128;
  const int t = threadIdx.x;
  const int lane = t & 63;
  const int wid = t >> 6;
  const int wr = wid >> 1, wc = wid & 1;
  const int fr = lane & 15, fq = lane >> 4;

  f32x4 acc[4][4];
#pragma unroll
  for (int i = 0; i < 4; ++i)
#pragma unroll
    for (int j = 0; j < 4; ++j) acc[i][j] = (f32x4){0.f, 0.f, 0.f, 0.f};

  const char* Ab = (const char*)A;
  const char* Bb = (const char*)B;

  for (int k0 = 0; k0 < 768; k0 += 64) {
#pragma unroll
    for (int p = 0; p < 4; ++p) {
      int idx = p * 256 + t;
      int row = idx >> 3;
      int scb = ((idx & 7) << 4) ^ ((row & 7) << 4);
      char* dstA = (char*)As + (p * 256 + (wid << 6)) * 16;
      char* dstB = (char*)Bs + (p * 256 + (wid << 6)) * 16;
      gload16(Ab + (size_t)(m0 + row) * 1536 + (size_t)k0 * 2 + scb, dstA);
      gload16(Bb + (size_t)(n0 + row) * 1536 + (size_t)k0 * 2 + scb, dstB);
    }
    __syncthreads();

    s16x8 af[4][2], bfr[4][2];
#pragma unroll
    for (int mi = 0; mi < 4; ++mi)
#pragma unroll
      for (int kk = 0; kk < 2; ++kk) {
        int row = wr * 64 + mi * 16 + fr;
        int cb = (kk * 64 + (fq << 4)) ^ ((row & 7) << 4);
        af[mi][kk] = *(const s16x8*)((const char*)As + row * 128 + cb);
      }
#pragma unroll
    for (int ni = 0; ni < 4; ++ni)
#pragma unroll
      for (int kk = 0; kk < 2; ++kk) {
        int row = wc * 64 + ni * 16 + fr;
        int cb = (kk * 64 + (fq << 4)) ^ ((row & 7) << 4);
        bfr[ni][kk] = *(const s16x8*)((const char*)Bs + row * 128 + cb);
      }
    __builtin_amdgcn_s_setprio(1);
#pragma unroll
    for (int kk = 0; kk < 2; ++kk)
#pragma unroll
      for (int mi = 0; mi < 4; ++mi)
#pragma unroll
        for (int ni = 0; ni < 4; ++ni)
          acc[mi][ni] = __builtin_amdgcn_mfma_f32_16x16x32_bf16(
              af[mi][kk], bfr[ni][kk], acc[mi][ni], 0, 0, 0);
    __builtin_amdgcn_s_setprio(0);
    __syncthreads();
  }

#pragma unroll
  for (int mi = 0; mi < 4; ++mi) {
#pragma unroll
    for (int ni = 0; ni < 4; ++ni) {
      int row0 = m0 + wr * 64 + mi * 16 + (fq << 2);
      int col = n0 + wc * 64 + ni * 16 + fr;
      if (isqv) {
        if (n0 < 768) {
          // q natural [m][col]
#pragma unroll
          for (int j = 0; j < 4; ++j)
            qbuf[(size_t)(row0 + j) * 768 + col] = f2bf(acc[mi][ni][j]);
        } else {
          // v transposed: Vt[col-768][m]
          u16x4 pk;
#pragma unroll
          for (int j = 0; j < 4; ++j) pk[j] = f2bf(acc[mi][ni][j]);
          *(u16x4*)(vtbuf + (size_t)(col - 768) * 4096 + row0) = pk;
        }
      } else {
        // k, scaled by 0.125/ln2 (log2-domain softmax)
#pragma unroll
        for (int j = 0; j < 4; ++j)
          kbuf[(size_t)(row0 + j) * 768 + col] = f2bf(acc[mi][ni][j] * 0.18033688f);
      }
    }
  }
}

// ---------------- final projection: out = y @ Wp^T + b (f32 out) ------------
__global__ __launch_bounds__(256) void gemm_out(
    const unsigned short* __restrict__ A, const unsigned short* __restrict__ B,
    float* __restrict__ outp, const float* __restrict__ bias) {
  __shared__ __align__(16) unsigned short As[128 * 64];
  __shared__ __align__(16) unsigned short Bs[128 * 64];
  const int t = threadIdx.x;
  const int lane = t & 63;
  const int wid = t >> 6;
  const int wr = wid >> 1, wc = wid & 1;
  const int m0 = blockIdx.x * 128, n0 = blockIdx.y * 128;
  const int fr = lane & 15, fq = lane >> 4;

  f32x4 acc[4][4];
#pragma unroll
  for (int i = 0; i < 4; ++i)
#pragma unroll
    for (int j = 0; j < 4; ++j) acc[i][j] = (f32x4){0.f, 0.f, 0.f, 0.f};

  for (int k0 = 0; k0 < 768; k0 += 64) {
#pragma unroll
    for (int p = 0; p < 4; ++p) {
      int idx = p * 256 + t;
      int row = idx >> 3;
      int scb = ((idx & 7) << 4) ^ ((row & 7) << 4);
      char* dstA = (char*)As + (p * 256 + (wid << 6)) * 16;
      char* dstB = (char*)Bs + (p * 256 + (wid << 6)) * 16;
      gload16((const char*)A + (size_t)(m0 + row) * 1536 + (size_t)k0 * 2 + scb, dstA);
      gload16((const char*)B + (size_t)(n0 + row) * 1536 + (size_t)k0 * 2 + scb, dstB);
    }
    __syncthreads();

    s16x8 af[4][2], bfr[4][2];
#pragma unroll
    for (int mi = 0; mi < 4; ++mi)
#pragma unroll
      for (int kk = 0; kk < 2; ++kk) {
        int row = wr * 64 + mi * 16 + fr;
        int cb = (kk * 64 + (fq << 4)) ^ ((row & 7) << 4);
        af[mi][kk] = *(const s16x8*)((const char*)As + row * 128 + cb);
      }
#pragma unroll
    for (int ni = 0; ni < 4; ++ni)
#pragma unroll
      for (int kk = 0; kk < 2; ++kk) {
        int row = wc * 64 + ni * 16 + fr;
        int cb = (kk * 64 + (fq << 4)) ^ ((row & 7) << 4);
        bfr[ni][kk] = *(const s16x8*)((const char*)Bs + row * 128 + cb);
      }
    __builtin_amdgcn_s_setprio(1);
#pragma unroll
    for (int kk = 0; kk < 2; ++kk)
#pragma unroll
      for (int mi = 0; mi < 4; ++mi)
#pragma unroll
        for (int ni = 0; ni < 4; ++ni)
          acc[mi][ni] = __builtin_amdgcn_mfma_f32_16x16x32_bf16(
              af[mi][kk], bfr[ni][kk], acc[mi][ni], 0, 0, 0);
    __builtin_amdgcn_s_setprio(0);
    __syncthreads();
  }

#pragma unroll
  for (int mi = 0; mi < 4; ++mi) {
#pragma unroll
    for (int ni = 0; ni < 4; ++ni) {
      int row0 = m0 + wr * 64 + mi * 16 + (fq << 2);
      int col = n0 + wc * 64 + ni * 16 + fr;
      float bv = bias[col];
#pragma unroll
      for (int j = 0; j < 4; ++j)
        outp[(size_t)(row0 + j) * 768 + col] = acc[mi][ni][j] + bv;
    }
  }
}

// ---------------- Flash attention, 32x32 MFMA, lane-local softmax ----------
// Qk = kbuf [4096][768] prescaled by 0.125/ln2 (flash-Q)
// Kq = qbuf [4096][768] (flash-K);  Vt [768][4096];  Y [4096][768]
// Per block: 128 q-rows, 4 waves x 32 rows. KVBLK=64, double-buffered.
// QK^T swapped: D[m][n] = sum_d K[m][d]*Q[n][d]; lane holds n=lane&31,
// rows m = (reg&3)+8*(reg>>2)+4*half (half=lane>>5), 2 m-tiles of 32.
// P relayout to PV B-fragments via per-wave swizzled LDS (r2-verified path).
__global__ __launch_bounds__(256, 2) void attn_kernel(
    const unsigned short* __restrict__ Qk, const unsigned short* __restrict__ Kq,
    const unsigned short* __restrict__ Vt, unsigned short* __restrict__ Y) {
  __shared__ __align__(16) unsigned short Ks[2][64 * 64];
  __shared__ __align__(16) unsigned short Vs[2][64 * 64];
  __shared__ __align__(16) unsigned short Ps[4][32 * 64];  // per-wave [n31][m64]
  const int t = threadIdx.x, lane = t & 63, wid = t >> 6;
  const int half = lane >> 5, l31 = lane & 31;

  // XCD-aware bijective swizzle of the 384-block grid (48 chunks per XCD)
  int bid = blockIdx.x;
  int f = (bid & 7) * 48 + (bid >> 3);
  const int h = f >> 5;            // head 0..11
  const int n0 = (f & 31) * 128;   // q-tile base

  // Q fragments (B-operand): lane holds col n=l31, k=d = half*8+j per kc slice
  s16x8 qf[4];
  {
    const size_t qrow = n0 + wid * 32 + l31;
#pragma unroll
    for (int kc = 0; kc < 4; ++kc)
      qf[kc] = *(const s16x8*)(Qk + qrow * 768 + h * 64 + kc * 16 + half * 8);
  }

  f32x16 o[2];
#pragma unroll
  for (int dt = 0; dt < 2; ++dt)
#pragma unroll
    for (int r = 0; r < 16; ++r) o[dt][r] = 0.f;
  float mold = -__builtin_inff();
  float lsum = 0.f;

  // per-lane LDS read offsets (iter-invariant): row = tile*32 + l31
  const int rswz = (l31 & 7) << 4;
  const int rbase = l31 * 128;
  int coff[4];
#pragma unroll
  for (int kc = 0; kc < 4; ++kc)
    coff[kc] = (kc * 32 + half * 16) ^ rswz;

  char* Pb = (char*)Ps[wid] + l31 * 128;  // per-wave P row (n = l31)

  auto stage = [&](int buf, int m0) {
#pragma unroll
    for (int p = 0; p < 2; ++p) {
      int idx = p * 256 + t;
      int row = idx >> 3;
      int scb = ((idx & 7) << 4) ^ ((row & 7) << 4);
      char* dk = (char*)Ks[buf] + (p * 256 + (wid << 6)) * 16;
      char* dv = (char*)Vs[buf] + (p * 256 + (wid << 6)) * 16;
      gload16((const char*)Kq + (size_t)(m0 + row) * 1536 + h * 128 + scb, dk);
      gload16((const char*)Vt + (size_t)(h * 64 + row) * 8192 + (size_t)m0 * 2 + scb, dv);
    }
  };

  stage(0, 0);
  __syncthreads();

  for (int it = 0; it < 64; ++it) {
    const int buf = it & 1;
    if (it < 63) stage(buf ^ 1, (it + 1) * 64);  // prefetch; drained at barrier

    const char* Ksb = (const char*)Ks[buf];
    const char* Vsb = (const char*)Vs[buf];

    // ---- QK^T: s[mt] = K-tile(mt) x Q
    f32x16 s[2];
#pragma unroll
    for (int mt = 0; mt < 2; ++mt)
#pragma unroll
      for (int r = 0; r < 16; ++r) s[mt][r] = 0.f;
    __builtin_amdgcn_s_setprio(1);
#pragma unroll
    for (int mt = 0; mt < 2; ++mt)
#pragma unroll
      for (int kc = 0; kc < 4; ++kc) {
        s16x8 kf = *(const s16x8*)(Ksb + mt * 4096 + rbase + coff[kc]);
        s[mt] = __builtin_amdgcn_mfma_f32_32x32x16_bf16(kf, qf[kc], s[mt], 0, 0, 0);
      }
    __builtin_amdgcn_s_setprio(0);

    // ---- lane-local online softmax (log2 domain); q-row = l31
    float mx[16];
#pragma unroll
    for (int r = 0; r < 16; ++r) mx[r] = fmaxf(s[0][r], s[1][r]);
#pragma unroll
    for (int st = 8; st >= 1; st >>= 1)
#pragma unroll
      for (int r = 0; r < st; ++r) mx[r] = fmaxf(mx[r], mx[r + st]);
    float pmax = fmaxf(mx[0], __shfl_xor(mx[0], 32));

    if (!__all(pmax - mold <= 8.f)) {  // defer-max (THR=8 in log2 units)
      float mn = fmaxf(mold, pmax);
      float sc = __builtin_exp2f(mold - mn);  // -inf -> 0 on first tile
      mold = mn;
      lsum *= sc;
#pragma unroll
      for (int dt = 0; dt < 2; ++dt)
#pragma unroll
        for (int r = 0; r < 16; ++r) o[dt][r] *= sc;
    }

    // p = exp2(s - mold); row-sum; pack P to per-wave LDS [n][m] (swizzled)
    f32x16 p[2];
#pragma unroll
    for (int mt = 0; mt < 2; ++mt)
#pragma unroll
      for (int r = 0; r < 16; ++r) p[mt][r] = __builtin_exp2f(s[mt][r] - mold);
    float ad[16];
#pragma unroll
    for (int r = 0; r < 16; ++r) ad[r] = p[0][r] + p[1][r];
#pragma unroll
    for (int st = 8; st >= 1; st >>= 1)
#pragma unroll
      for (int r = 0; r < st; ++r) ad[r] += ad[r + st];
    lsum += ad[0] + __shfl_xor(ad[0], 32);

    // lane's p[mt][r] = P[m = mt*32 + (r&3)+8*(r>>2)+4*half][n=l31]
    // write pairs so row n holds m ascending: {w0,w1}->m(8h..8h+3) block mt*64,
    // {w2,w3}->m(8+8h..), {w4,w5}->m(16+8h..), {w6,w7}->m(24+8h..)
#pragma unroll
    for (int mt = 0; mt < 2; ++mt) {
      unsigned int w[8];
#pragma unroll
      for (int i = 0; i < 8; ++i) w[i] = cvtpk(p[mt][2 * i], p[mt][2 * i + 1]);
#pragma unroll
      for (int g = 0; g < 4; ++g) {
        uint2 u;
        u.x = w[2 * g];
        u.y = w[2 * g + 1];
        *(uint2*)(Pb + (((mt * 64 + g * 16) ^ rswz) + 8 * half)) = u;
      }
    }

    // read PV B-fragments: lane holds P[m = kc*16 + 8*half + j][n=l31]
    s16x8 pfr[4];
#pragma unroll
    for (int kc = 0; kc < 4; ++kc)
      pfr[kc] = *(const s16x8*)(Pb + (((kc * 32 + 16 * half) ^ rswz)));

    // ---- PV: o[dt] += Vt-tile(dt) x P   (D[d][n], k = m)
    __builtin_amdgcn_s_setprio(1);
#pragma unroll
    for (int dt = 0; dt < 2; ++dt)
#pragma unroll
      for (int kc = 0; kc < 4; ++kc) {
        s16x8 vf = *(const s16x8*)(Vsb + dt * 4096 + rbase + coff[kc]);
        o[dt] = __builtin_amdgcn_mfma_f32_32x32x16_bf16(vf, pfr[kc], o[dt], 0, 0, 0);
      }
    __builtin_amdgcn_s_setprio(0);
    __syncthreads();
  }

  // ---- epilogue: y = o / lsum, all lane-local
  const float inv = 1.0f / lsum;
  const size_t n = n0 + wid * 32 + l31;
#pragma unroll
  for (int dt = 0; dt < 2; ++dt)
#pragma unroll
    for (int g = 0; g < 4; ++g) {
      u16x4 pk;
#pragma unroll
      for (int e = 0; e < 4; ++e) pk[e] = f2bf(o[dt][4 * g + e] * inv);
      int d = dt * 32 + 8 * g + 4 * half;
      *(u16x4*)(Y + n * 768 + h * 64 + d) = pk;
    }
}

// ---------------- launch ----------------
extern "C" void kernel_launch(void* const* d_in, const int* in_sizes, int n_in,
                              void* d_out, int out_size, void* d_ws,
                              size_t ws_size, hipStream_t stream) {
  const float* x = (const float*)d_in[0];    // (4096, 768)
  const float* src = (const float*)d_in[1];  // (4096, 768)
  const float* Wqv = (const float*)d_in[2];  // (1536, 768)
  const float* Wk = (const float*)d_in[3];   // (768, 768)
  const float* Wp = (const float*)d_in[4];   // (768, 768)
  const float* bp = (const float*)d_in[5];   // (768,)
  float* out = (float*)d_out;

  char* ws = (char*)d_ws;
  unsigned short* srcb = (unsigned short*)(ws + 0);          // 4096x768
  unsigned short* xb   = (unsigned short*)(ws + 6291456);    // 4096x768
  unsigned short* wqvb = (unsigned short*)(ws + 12582912);   // 1536x768
  unsigned short* wkb  = (unsigned short*)(ws + 14942208);   // 768x768
  unsigned short* wpb  = (unsigned short*)(ws + 16121856);   // 768x768
  unsigned short* qbuf = (unsigned short*)(ws + 17301504);   // 4096x768
  unsigned short* vtbuf= (unsigned short*)(ws + 23592960);   // 768x4096
  unsigned short* kbuf = (unsigned short*)(ws + 29884416);   // 4096x768
  unsigned short* ybuf = (unsigned short*)(ws + 36175872);   // 4096x768

  cvt_bf16_multi<<<8448, 256, 0, stream>>>(src, x, Wqv, Wk, Wp, srcb, xb, wqvb,
                                           wkb, wpb);

  // qv = src @ Wqv^T (q natural, v transposed) + k = (x @ Wk^T) * scale
  gemm_proj<<<dim3(32, 18), 256, 0, stream>>>(srcb, wqvb, xb, wkb, qbuf, vtbuf,
                                              kbuf);
  // attention (swizzled 1-D grid of 384)
  attn_kernel<<<384, 256, 0, stream>>>(kbuf, qbuf, vtbuf, ybuf);
  // out = y @ Wp^T + b
  gemm_out<<<dim3(32, 6), 256, 0, stream>>>(ybuf, wpb, out, bp);
}